// Round 15
// baseline (33.870 us; speedup 1.0000x reference)
//
#include <hip/hip_runtime.h>

#define NB 64
#define NK 49
#define NL 200
#define ND 36
#define LD (NL*ND)              // 7200

// workspace layout (float offsets) — both arrays d-major for contiguous K2 streams
#define AT_FLOATS  (LD*NB*4)                    // At3[d][l][b][4] = {x,t,m,pd}
#define WPK_FLOATS (LD*NK*6)                    // Wpk3[d][ks][l][42] = 7 x {wt0..3, 4*bt, wv}
#define WPK_OFF   AT_FLOATS
#define WS_PACK_BYTES ((size_t)(AT_FLOATS + WPK_FLOATS) * 4)

#define LOG2E 1.44269504088896f

#if __has_builtin(__builtin_amdgcn_exp2f)
#define EXP2F(x) __builtin_amdgcn_exp2f(x)
#else
#define EXP2F(x) __expf((x) * 0.6931471805599453f)
#endif

// native 4-float vector for nontemporal builtins (HIP float4 is a struct, not native)
typedef float nf4 __attribute__((ext_vector_type(4)));

static __device__ __forceinline__ float4 nt_load4(const float4* p) {
    nf4 r = __builtin_nontemporal_load((const nf4*)p);
    float4 v; v.x = r.x; v.y = r.y; v.z = r.z; v.w = r.w; return v;
}
static __device__ __forceinline__ void nt_store4(float4* p, float4 v) {
    nf4 r; r.x = v.x; r.y = v.y; r.z = v.z; r.w = v.w;
    __builtin_nontemporal_store(r, (nf4*)p);
}

// ---------------- K1: pack (R8 structure) with NON-TEMPORAL input reads + ws writes --------
// nt stores keep At/Wpk lines out of the writer XCD's L2 dirty state -> K2's cold
// reads fetch clean lines from L3 instead of cross-XCD dirty-line snoops.
__global__ __launch_bounds__(256) void alnn_pack_nt(
    const float* __restrict__ X, const float* __restrict__ T,
    const float* __restrict__ M, const float* __restrict__ PD,
    const float* __restrict__ w_v, const float4* __restrict__ w_t,
    const float* __restrict__ b_t, float* __restrict__ ws)
{
    __shared__ float tile[9440];
    const int bid = blockIdx.x, t = threadIdx.x;

    if (bid < 225) {
        // activations: 32 ld x 64 b x {X,T,M,PD} -> At3[d][l][b]; LDS [a][b][33]
        const int ld0 = bid * 32;
        const int ld = t & 31, bq = t >> 5;
        const float* src[4] = {X, T, M, PD};
        #pragma unroll
        for (int a = 0; a < 4; a++) {
            const float* A = src[a];
            for (int b = bq; b < 64; b += 8)
                tile[(a * 64 + b) * 33 + ld] =
                    __builtin_nontemporal_load(&A[(size_t)b * LD + ld0 + ld]);
        }
        __syncthreads();
        float4* At4 = (float4*)ws;
        const int b = t & 63, ldq = t >> 6;
        #pragma unroll
        for (int r = 0; r < 8; r++) {
            const int l_local = ldq * 8 + r;
            const int ldg = ld0 + l_local;
            const int l = ldg / ND, d = ldg - l * ND;
            float4 v;
            v.x = tile[(0 * 64 + b) * 33 + l_local];
            v.y = tile[(1 * 64 + b) * 33 + l_local];
            v.z = tile[(2 * 64 + b) * 33 + l_local];
            v.w = tile[(3 * 64 + b) * 33 + l_local];
            nt_store4(&At4[((size_t)d * NL + l) * 64 + b], v);
        }
    } else {
        // weights: 32 ld x 49 k; LDS tile [ld][295] (odd stride); k = ks*7+kk
        const int ld0 = (bid - 225) * 32;
        const int ld = t & 31, kq = t >> 5;
        for (int k = kq; k < NK; k += 8) {
            const float4 wt = nt_load4(&w_t[(size_t)k * LD + ld0 + ld]);
            const float  bt = __builtin_nontemporal_load(&b_t[(size_t)k * LD + ld0 + ld]);
            const float  wv = __builtin_nontemporal_load(&w_v[(size_t)k * LD + ld0 + ld]);
            float* w = tile + ld * 295 + k * 6;
            w[0] = wt.x; w[1] = wt.y; w[2] = wt.z; w[3] = wt.w;
            w[4] = 4.0f * bt; w[5] = wv;
        }
        __syncthreads();
        // write d-major: Wpk3[((d*7 + ks)*200 + l)*42 + c]
        float* Wpk = ws + WPK_OFF;
        for (int i = t; i < 7 * 32 * 42; i += 256) {
            const int ks = i / 1344, rem = i - ks * 1344;
            const int l_local = rem / 42, c = rem - l_local * 42;
            const int ldg = ld0 + l_local;
            const int l = ldg / ND, d = ldg - l * ND;
            __builtin_nontemporal_store(tile[l_local * 295 + ks * 42 + c],
                &Wpk[(((size_t)d * 7 + ks) * NL + l) * 42 + c]);
        }
    }
}

// ---------------- K2: fused compute + reduce (R8-identical compute path) ------------------
// grid 252 = (d:36) x (ks:7); block 1024 = 16 waves; lane=b; wave covers 12-13 l x 7 k.
__global__ __launch_bounds__(1024) void alnn_main11(
    const float* __restrict__ ws_ro, const float* __restrict__ alpha,
    const float* __restrict__ b_v, float* __restrict__ out)
{
    __shared__ float red[16 * 7 * 64];                   // 28,672 B

    // bijective chunked XCD swizzle (nwg=252: q=31, r=4): the 7 ks-blocks of one d
    // stay on one XCD -> each At d-slab is pulled into exactly one L2.
    const int orig = blockIdx.x;
    const int xcd  = orig & 7, slot = orig >> 3;
    const int base = (xcd < 4) ? xcd * 32 : 128 + (xcd - 4) * 31;
    const int job  = base + slot;

    const int d  = job / 7, ks = job - (job / 7) * 7;
    const int t  = threadIdx.x;
    const int b  = t & 63;
    const int w  = __builtin_amdgcn_readfirstlane(t >> 6);   // wave id 0..15 (SGPR)
    const int k0 = ks * 7;

    const float4* At4 = (const float4*)ws_ro + (size_t)d * NL * 64;          // d-slab
    const float*  Ws  = ws_ro + WPK_OFF + ((size_t)d * 7 + ks) * NL * 42;    // contiguous slab

    float arn[7], rk[7];
    #pragma unroll
    for (int kk = 0; kk < 7; kk++) {
        arn[kk] = -fmaxf(alpha[k0 + kk], 0.0f) * LOG2E;
        rk[kk]  = (float)(k0 + kk);
    }

    float acc[7] = {0, 0, 0, 0, 0, 0, 0};

    const int len  = (w < 8) ? 13 : 12;
    const int lbeg = (w < 8) ? 13 * w : 104 + 12 * (w - 8);

    for (int ll = 0; ll < len; ll++) {
        const int l = lbeg + ll;
        const float4 av = At4[(size_t)l * 64 + b];
        const float xp = fmaxf(av.x, 0.0f);              // relu(x*e) == relu(x)*e, e>0
        const float* wr = Ws + (size_t)l * 42;           // wave-uniform -> s_load stream
        #pragma unroll
        for (int kk = 0; kk < 7; kk++) {
            const float dist = fabsf(av.y - rk[kk]);
            const float e    = EXP2F(arn[kk] * dist);
            float s = fmaf(wr[kk*6+0], av.x,
                      fmaf(wr[kk*6+1], xp * e,
                      fmaf(wr[kk*6+2], av.z,
                      fmaf(wr[kk*6+3], av.w, wr[kk*6+4]))));
            acc[kk] = fmaf(wr[kk*6+5], fmaxf(s, 0.0f), acc[kk]);
        }
    }

    #pragma unroll
    for (int kk = 0; kk < 7; kk++)
        red[(w * 7 + kk) * 64 + b] = acc[kk];
    __syncthreads();

    if (w < 7) {
        const int kk = w, k = k0 + kk;
        float sum = 0.0f;
        #pragma unroll
        for (int ww = 0; ww < 16; ww++)
            sum += red[(ww * 7 + kk) * 64 + b];
        __builtin_nontemporal_store(
            fmaxf(sum + 200.0f * b_v[k * ND + d], 0.0f),
            &out[((size_t)b * NK + k) * ND + d]);
    }
}

// ---------------- legacy fallback (proven round-1 kernel) ----------------------------------
__global__ __launch_bounds__(256) void alnn_fused_kernel(
    const float* __restrict__ X, const float* __restrict__ T,
    const float* __restrict__ M, const float* __restrict__ PD,
    const float* __restrict__ alpha, const float* __restrict__ w_v,
    const float4* __restrict__ w_t, const float* __restrict__ b_v,
    const float* __restrict__ b_t, float* __restrict__ out)
{
    const int bk = blockIdx.x;
    const int k  = bk % NK;
    const int b  = bk / NK;
    const int t  = threadIdx.x;

    __shared__ float part[7][ND];

    const float alpha_k = fmaxf(alpha[k], 0.0f);
    const float refk    = (float)k;

    if (t < 7 * ND) {
        const int d = t % ND;
        const int j = t / ND;
        const float*  Xp  = X   + (size_t)b * LD + d;
        const float*  Tp  = T   + (size_t)b * LD + d;
        const float*  Mp  = M   + (size_t)b * LD + d;
        const float*  Pp  = PD  + (size_t)b * LD + d;
        const float*  wvp = w_v + (size_t)k * LD + d;
        const float*  btp = b_t + (size_t)k * LD + d;
        const float4* wtp = w_t + (size_t)k * LD + d;

        float acc = 0.0f;
        for (int l = j; l < NL; l += 7) {
            const int o = l * ND;
            const float x  = Xp[o];
            const float tt = Tp[o];
            const float m  = Mp[o];
            const float pd = Pp[o];
            const float4 wv4 = wtp[o];
            const float bt = btp[o];
            const float dist  = fabsf(tt - refk);
            const float e     = __expf(-alpha_k * dist);
            const float inten = fmaxf(x * e, 0.0f);
            float s = fmaf(wv4.x, x, fmaf(wv4.y, inten, fmaf(wv4.z, m, fmaf(wv4.w, pd, 4.0f * bt))));
            s = fmaxf(s, 0.0f);
            acc = fmaf(wvp[o], s, acc);
        }
        part[j][d] = acc;
    }
    __syncthreads();

    if (t < ND) {
        float sum = 0.0f;
        #pragma unroll
        for (int j = 0; j < 7; ++j) sum += part[j][t];
        sum += (float)NL * b_v[k * ND + t];
        out[(size_t)bk * ND + t] = fmaxf(sum, 0.0f);
    }
}

extern "C" void kernel_launch(void* const* d_in, const int* in_sizes, int n_in,
                              void* d_out, int out_size, void* d_ws, size_t ws_size,
                              hipStream_t stream) {
    const float* X     = (const float*)d_in[0];
    const float* T     = (const float*)d_in[1];
    const float* M     = (const float*)d_in[2];
    const float* PD    = (const float*)d_in[3];
    const float* alpha = (const float*)d_in[4];
    const float* w_v   = (const float*)d_in[5];
    const float* w_t   = (const float*)d_in[6];
    const float* b_v   = (const float*)d_in[7];
    const float* b_t   = (const float*)d_in[8];
    float* out = (float*)d_out;
    float* ws  = (float*)d_ws;

    if (ws_size >= WS_PACK_BYTES) {
        alnn_pack_nt<<<450, 256, 0, stream>>>(X, T, M, PD, w_v, (const float4*)w_t, b_t, ws);
        alnn_main11<<<252, 1024, 0, stream>>>(ws, alpha, b_v, out);
    } else {
        alnn_fused_kernel<<<NB * NK, 256, 0, stream>>>(
            X, T, M, PD, alpha, w_v, (const float4*)w_t, b_v, b_t, out);
    }
}

// Round 16
// 31.098 us; speedup vs baseline: 1.0891x; 1.0891x over previous
//
#include <hip/hip_runtime.h>

#define NB 64
#define NK 49
#define NL 200
#define ND 36
#define LD (NL*ND)              // 7200
#define NCH 16                  // l-chunks
#define NDG 18                  // d-pair groups (2 d each)
#define OUTSZ (NB*NK*ND)        // 112,896

// workspace: only l-chunk partials part[lc][dg][kd][b]
#define WS_NEED_BYTES ((size_t)NCH * OUTSZ * 4)

#define LOG2E 1.44269504088896f

#if __has_builtin(__builtin_amdgcn_exp2f)
#define EXP2F(x) __builtin_amdgcn_exp2f(x)
#else
#define EXP2F(x) __expf((x) * 0.6931471805599453f)
#endif

// =================== K1: single-pass fused kernel ==========================================
// grid 288 = (lc:16) x (dg:18); block 512 = 8 waves; lane = b.
// Block stages A[64b][len l][2d] + W[49k][len l][2d] in LDS, computes all 49 k for its
// (l-chunk, d-pair), writes per-chunk partials. No transpose kernel, no cross-wave reduce.
__global__ __launch_bounds__(512) void alnn_onepass(
    const float* __restrict__ X, const float* __restrict__ T,
    const float* __restrict__ M, const float* __restrict__ PD,
    const float* __restrict__ alpha, const float* __restrict__ w_v,
    const float4* __restrict__ w_t4, const float* __restrict__ b_t,
    float* __restrict__ part)
{
    __shared__ float At_lds[13 * 2 * 64 * 4];            // 26,624 B  [ll][dl][b][arr]
    __shared__ float Wl[13 * NK * 2 * 6];                // 30,576 B  [ll][k][dl][6]

    // exact 8x36 XCD chunking: XCD x owns jobs 36x..36x+35 = lc in {2x,2x+1} x all dg
    // -> every input line for an l-slice is fetched into exactly one L2.
    const int orig = blockIdx.x;
    const int job  = (orig & 7) * 36 + (orig >> 3);
    const int lc   = job / NDG, dg = job - (job / NDG) * NDG;
    const int d0   = dg * 2;

    const int t   = threadIdx.x;
    const int b   = t & 63;
    const int w   = __builtin_amdgcn_readfirstlane(t >> 6);  // wave 0..7
    const int len = (lc < 8) ? 13 : 12;
    const int l0  = (lc < 8) ? 13 * lc : 104 + 12 * (lc - 8);

    // ---- stage A: 4 arrays x 64 b x len l, 8 B (2 d) per run ----
    {
        const float* srcs[4] = {X, T, M, PD};
        const int total = 4 * 64 * len;                  // <= 3328
        for (int i = t; i < total; i += 512) {
            const int arr = i & 3, bb = (i >> 2) & 63, ll = i >> 8;
            const float2 v = *(const float2*)(srcs[arr] + (size_t)bb * LD + (l0 + ll) * ND + d0);
            At_lds[((ll * 2 + 0) * 64 + bb) * 4 + arr] = v.x;
            At_lds[((ll * 2 + 1) * 64 + bb) * 4 + arr] = v.y;
        }
    }
    // ---- stage W: 49 k x len l, rows {wt0..3, 4*bt, wv} per d ----
    {
        const int total = NK * len;                      // <= 637
        for (int i = t; i < total; i += 512) {
            const int k = i % NK, ll = i / NK;
            const size_t base = (size_t)k * LD + (l0 + ll) * ND + d0;
            const float4 wtA = w_t4[base];
            const float4 wtB = w_t4[base + 1];
            const float2 bt2 = *(const float2*)(b_t + base);
            const float2 wv2 = *(const float2*)(w_v + base);
            float* r = Wl + ((ll * NK + k) * 2) * 6;
            r[0] = wtA.x; r[1] = wtA.y; r[2] = wtA.z; r[3] = wtA.w;
            r[4] = 4.0f * bt2.x; r[5] = wv2.x;
            r[6] = wtB.x; r[7] = wtB.y; r[8] = wtB.z; r[9] = wtB.w;
            r[10] = 4.0f * bt2.y; r[11] = wv2.y;
        }
    }
    __syncthreads();

    // ---- compute: wave w owns kd-range; kd = k*2+dl; wave0: kd 0..13, else 12w+2..12w+13 ----
    const int npair = (w == 0) ? 7 : 6;                  // k-pairs (each pair = d0,d1)
    const int kbase = (w == 0) ? 0 : 6 * w + 1;
    const int kd0   = kbase * 2;

    float arn[7], rk[7];
    #pragma unroll
    for (int j = 0; j < 7; j++) {
        const int k = kbase + ((j < npair) ? j : (npair - 1));
        arn[j] = -fmaxf(alpha[k], 0.0f) * LOG2E;
        rk[j]  = (float)k;
    }

    float acc0[7] = {0, 0, 0, 0, 0, 0, 0};
    float acc1[7] = {0, 0, 0, 0, 0, 0, 0};

    const float4* At4 = (const float4*)At_lds;
    for (int ll = 0; ll < len; ll++) {
        const float4 av0 = At4[(ll * 2 + 0) * 64 + b];
        const float4 av1 = At4[(ll * 2 + 1) * 64 + b];
        const float xp0 = fmaxf(av0.x, 0.0f);            // relu(x*e) == relu(x)*e, e>0
        const float xp1 = fmaxf(av1.x, 0.0f);
        #pragma unroll
        for (int j = 0; j < 7; j++) {
            if (j < npair) {
                const int k = kbase + j;
                const float* r = Wl + ((ll * NK + k) * 2) * 6;   // wave-uniform -> broadcast
                const float e0 = EXP2F(arn[j] * fabsf(av0.y - rk[j]));
                const float e1 = EXP2F(arn[j] * fabsf(av1.y - rk[j]));
                float s0 = fmaf(r[0], av0.x, fmaf(r[1], xp0 * e0,
                           fmaf(r[2], av0.z, fmaf(r[3], av0.w, r[4]))));
                float s1 = fmaf(r[6], av1.x, fmaf(r[7], xp1 * e1,
                           fmaf(r[8], av1.z, fmaf(r[9], av1.w, r[10]))));
                acc0[j] = fmaf(r[5],  fmaxf(s0, 0.0f), acc0[j]);
                acc1[j] = fmaf(r[11], fmaxf(s1, 0.0f), acc1[j]);
            }
        }
    }

    // ---- per-chunk partial store (coalesced in b; no cross-wave reduce needed) ----
    float* pdst = part + (size_t)lc * OUTSZ + (size_t)dg * (98 * 64);
    #pragma unroll
    for (int j = 0; j < 7; j++) {
        if (j < npair) {
            pdst[(kd0 + 2 * j + 0) * 64 + b] = acc0[j];
            pdst[(kd0 + 2 * j + 1) * 64 + b] = acc1[j];
        }
    }
}

// =================== K2: epilogue — sum 16 chunks + bias + relu ============================
__global__ __launch_bounds__(512) void alnn_epi16(
    const float* __restrict__ part, const float* __restrict__ b_v,
    float* __restrict__ out)
{
    const int i = blockIdx.x * 512 + threadIdx.x;
    if (i < OUTSZ) {
        float sum = 0.0f;
        #pragma unroll
        for (int c = 0; c < NCH; c++)
            sum += part[(size_t)c * OUTSZ + i];
        const int b  = i & 63;
        const int r  = i >> 6;
        const int kd = r % 98, dg = r / 98;
        const int k  = kd >> 1;
        const int d  = dg * 2 + (kd & 1);
        out[((size_t)b * NK + k) * ND + d] =
            fmaxf(sum + 200.0f * b_v[k * ND + d], 0.0f);
    }
}

// ---------------- legacy fallback (proven round-1 kernel) ----------------------------------
__global__ __launch_bounds__(256) void alnn_fused_kernel(
    const float* __restrict__ X, const float* __restrict__ T,
    const float* __restrict__ M, const float* __restrict__ PD,
    const float* __restrict__ alpha, const float* __restrict__ w_v,
    const float4* __restrict__ w_t, const float* __restrict__ b_v,
    const float* __restrict__ b_t, float* __restrict__ out)
{
    const int bk = blockIdx.x;
    const int k  = bk % NK;
    const int b  = bk / NK;
    const int t  = threadIdx.x;

    __shared__ float part[7][ND];

    const float alpha_k = fmaxf(alpha[k], 0.0f);
    const float refk    = (float)k;

    if (t < 7 * ND) {
        const int d = t % ND;
        const int j = t / ND;
        const float*  Xp  = X   + (size_t)b * LD + d;
        const float*  Tp  = T   + (size_t)b * LD + d;
        const float*  Mp  = M   + (size_t)b * LD + d;
        const float*  Pp  = PD  + (size_t)b * LD + d;
        const float*  wvp = w_v + (size_t)k * LD + d;
        const float*  btp = b_t + (size_t)k * LD + d;
        const float4* wtp = w_t + (size_t)k * LD + d;

        float acc = 0.0f;
        for (int l = j; l < NL; l += 7) {
            const int o = l * ND;
            const float x  = Xp[o];
            const float tt = Tp[o];
            const float m  = Mp[o];
            const float pd = Pp[o];
            const float4 wv4 = wtp[o];
            const float bt = btp[o];
            const float dist  = fabsf(tt - refk);
            const float e     = __expf(-alpha_k * dist);
            const float inten = fmaxf(x * e, 0.0f);
            float s = fmaf(wv4.x, x, fmaf(wv4.y, inten, fmaf(wv4.z, m, fmaf(wv4.w, pd, 4.0f * bt))));
            s = fmaxf(s, 0.0f);
            acc = fmaf(wvp[o], s, acc);
        }
        part[j][d] = acc;
    }
    __syncthreads();

    if (t < ND) {
        float sum = 0.0f;
        #pragma unroll
        for (int j = 0; j < 7; ++j) sum += part[j][t];
        sum += (float)NL * b_v[k * ND + t];
        out[(size_t)bk * ND + t] = fmaxf(sum, 0.0f);
    }
}

extern "C" void kernel_launch(void* const* d_in, const int* in_sizes, int n_in,
                              void* d_out, int out_size, void* d_ws, size_t ws_size,
                              hipStream_t stream) {
    const float* X     = (const float*)d_in[0];
    const float* T     = (const float*)d_in[1];
    const float* M     = (const float*)d_in[2];
    const float* PD    = (const float*)d_in[3];
    const float* alpha = (const float*)d_in[4];
    const float* w_v   = (const float*)d_in[5];
    const float* w_t   = (const float*)d_in[6];
    const float* b_v   = (const float*)d_in[7];
    const float* b_t   = (const float*)d_in[8];
    float* out = (float*)d_out;
    float* ws  = (float*)d_ws;

    if (ws_size >= WS_NEED_BYTES) {
        alnn_onepass<<<NCH * NDG, 512, 0, stream>>>(
            X, T, M, PD, alpha, w_v, (const float4*)w_t, b_t, ws);
        alnn_epi16<<<(OUTSZ + 511) / 512, 512, 0, stream>>>(ws, b_v, out);
    } else {
        alnn_fused_kernel<<<NB * NK, 256, 0, stream>>>(
            X, T, M, PD, alpha, w_v, (const float4*)w_t, b_v, b_t, out);
    }
}